// Round 2
// baseline (359.485 us; speedup 1.0000x reference)
//
#include <hip/hip_runtime.h>
#include <hip/hip_bf16.h>
#include <math.h>

#define T_SEQ 2048
#define DM 1024
#define NH 16
#define DH 64
#define CHUNK 128
#define NCHUNK (T_SEQ / CHUNK)   // 16

typedef __hip_bfloat16 bf16;
typedef __attribute__((ext_vector_type(8))) short short8;
typedef __attribute__((ext_vector_type(4))) float f32x4;

static __device__ __forceinline__ short f2b_bits(float f) {
  bf16 t = __float2bfloat16(f);
  short s;
  __builtin_memcpy(&s, &t, 2);
  return s;
}

// ---------------------------------------------------------------------------
// fp32 -> bf16 conversion (weights), float4 vectorized. n must be /4.
// ---------------------------------------------------------------------------
__global__ __launch_bounds__(256) void f2b_kernel(const float* __restrict__ in,
                                                  bf16* __restrict__ out, int n4) {
  int i = blockIdx.x * 256 + threadIdx.x;
  if (i >= n4) return;
  float4 v = ((const float4*)in)[i];
  typedef __attribute__((ext_vector_type(4))) short short4v;
  short4v s;
  s.x = f2b_bits(v.x); s.y = f2b_bits(v.y); s.z = f2b_bits(v.z); s.w = f2b_bits(v.w);
  *(short4v*)&out[i * 4] = s;
}

// ---------------------------------------------------------------------------
// LayerNorm (fp32 in) -> xn bf16, plus bf16 copy of raw x for gate GEMM.
// One block per row.
// ---------------------------------------------------------------------------
__global__ __launch_bounds__(256) void ln_kernel(const float* __restrict__ x,
                                                 const float* __restrict__ g,
                                                 const float* __restrict__ b,
                                                 bf16* __restrict__ xn,
                                                 bf16* __restrict__ xbf) {
  const int row = blockIdx.x;
  const float* xr = x + (size_t)row * DM;
  float vals[4];
  float s = 0.f, s2 = 0.f;
#pragma unroll
  for (int i = 0; i < 4; i++) {
    float v = xr[threadIdx.x + i * 256];
    vals[i] = v;
    s += v;
    s2 += v * v;
  }
#pragma unroll
  for (int m = 1; m < 64; m <<= 1) {
    s += __shfl_xor(s, m, 64);
    s2 += __shfl_xor(s2, m, 64);
  }
  __shared__ float red[8];
  const int wid = threadIdx.x >> 6;
  if ((threadIdx.x & 63) == 0) {
    red[wid] = s;
    red[4 + wid] = s2;
  }
  __syncthreads();
  s = red[0] + red[1] + red[2] + red[3];
  s2 = red[4] + red[5] + red[6] + red[7];
  const float mean = s * (1.f / DM);
  const float var = s2 * (1.f / DM) - mean * mean;
  const float rstd = rsqrtf(var + 1e-5f);
#pragma unroll
  for (int i = 0; i < 4; i++) {
    int idx = threadIdx.x + i * 256;
    float v = (vals[i] - mean) * rstd * g[idx] + b[idx];
    xn[(size_t)row * DM + idx] = __float2bfloat16(v);
    xbf[(size_t)row * DM + idx] = __float2bfloat16(vals[i]);
  }
}

// ---------------------------------------------------------------------------
// GEMM C = A(MxK,bf16) * W(NxK,bf16)^T + bias(fp32)
// MODE 0: gate  -> gate_sig fp32 = sigmoid(C)
// MODE 1: qkv   -> gated+ELU q,k and v scattered to [H][T][DH] fp32
// MODE 2: proj  -> fp32 to Cout
// Block: 256 threads (4 waves, 2x2 wave grid), tile 128x128, BK=32, K=1024.
// ---------------------------------------------------------------------------
template <int MODE>
__global__ __launch_bounds__(256) void gemm_bt(
    const bf16* __restrict__ A, const bf16* __restrict__ W,
    const float* __restrict__ bias,
    float* __restrict__ gate_sig, const float* __restrict__ inv_den,
    float* __restrict__ Qo, float* __restrict__ Ko, float* __restrict__ Vo,
    float* __restrict__ Cout) {
  constexpr int K = 1024;
  constexpr int LDS_STR = 56;  // shorts; 112B row stride: 16B aligned
  __shared__ __align__(16) short As[128 * LDS_STR];
  __shared__ __align__(16) short Bs[128 * LDS_STR];

  const int tid = threadIdx.x;
  const int wid = tid >> 6, lane = tid & 63;
  const int wm = wid >> 1, wn = wid & 1;
  const int lm = lane & 15, quad = lane >> 4;
  const int lr = tid >> 2;          // 0..63 staging row
  const int cg = (tid & 3) * 8;     // staging col offset (shorts)

  const int m0 = blockIdx.x * 128;
  const int n0 = blockIdx.y * 128;

  const short* Ag = (const short*)A;
  const short* Wg = (const short*)W;

  f32x4 zero = {0.f, 0.f, 0.f, 0.f};
  f32x4 acc[4][4];
#pragma unroll
  for (int i = 0; i < 4; i++)
#pragma unroll
    for (int j = 0; j < 4; j++) acc[i][j] = zero;

  for (int kb = 0; kb < K; kb += 32) {
    __syncthreads();
#pragma unroll
    for (int rr = 0; rr < 128; rr += 64) {
      const int row = lr + rr;
      *(short8*)&As[row * LDS_STR + cg] =
          *(const short8*)&Ag[(size_t)(m0 + row) * K + kb + cg];
      *(short8*)&Bs[row * LDS_STR + cg] =
          *(const short8*)&Wg[(size_t)(n0 + row) * K + kb + cg];
    }
    __syncthreads();
    short8 afr[4], bfr[4];
#pragma unroll
    for (int i = 0; i < 4; i++) {
      afr[i] = *(const short8*)&As[(wm * 64 + i * 16 + lm) * LDS_STR + quad * 8];
      bfr[i] = *(const short8*)&Bs[(wn * 64 + i * 16 + lm) * LDS_STR + quad * 8];
    }
#pragma unroll
    for (int i = 0; i < 4; i++)
#pragma unroll
      for (int j = 0; j < 4; j++)
        acc[i][j] = __builtin_amdgcn_mfma_f32_16x16x32_bf16(afr[i], bfr[j], acc[i][j], 0, 0, 0);
  }

  // epilogue: C/D layout col = lane&15, row = quad*4 + r
#pragma unroll
  for (int i = 0; i < 4; i++) {
    const int rbase = m0 + wm * 64 + i * 16 + quad * 4;
#pragma unroll
    for (int j = 0; j < 4; j++) {
      const int col = n0 + wn * 64 + j * 16 + lm;
      const float bval = bias[col];
#pragma unroll
      for (int r = 0; r < 4; r++) {
        const int row = rbase + r;
        float v = acc[i][j][r] + bval;
        if (MODE == 0) {
          gate_sig[(size_t)row * DM + col] = 1.f / (1.f + __expf(-v));
        } else if (MODE == 1) {
          if (col < DM) {
            const int d = col;
            float gn = gate_sig[(size_t)row * DM + d] * inv_den[row];
            float q = v * gn;
            q = q > 0.f ? q + 1.f : __expf(q);
            Qo[((size_t)(d >> 6) * T_SEQ + row) * DH + (d & 63)] = q;
          } else if (col < 2 * DM) {
            const int d = col - DM;
            float gn = gate_sig[(size_t)row * DM + d] * inv_den[row];
            float kk = v * gn;
            kk = kk > 0.f ? kk + 1.f : __expf(kk);
            Ko[((size_t)(d >> 6) * T_SEQ + row) * DH + (d & 63)] = kk;
          } else {
            const int d = col - 2 * DM;
            Vo[((size_t)(d >> 6) * T_SEQ + row) * DH + (d & 63)] = v;
          }
        } else {
          Cout[(size_t)row * DM + col] = v;
        }
      }
    }
  }
}

// ---------------------------------------------------------------------------
// Gate row mean -> inv_den[row] = 1/(mean + EPS_GATE)
// ---------------------------------------------------------------------------
__global__ __launch_bounds__(256) void gate_mean_kernel(const float* __restrict__ gate_sig,
                                                        float* __restrict__ inv_den) {
  const int row = blockIdx.x;
  float s = 0.f;
  for (int i = threadIdx.x; i < DM; i += 256) s += gate_sig[(size_t)row * DM + i];
#pragma unroll
  for (int m = 1; m < 64; m <<= 1) s += __shfl_xor(s, m, 64);
  __shared__ float red[4];
  if ((threadIdx.x & 63) == 0) red[threadIdx.x >> 6] = s;
  __syncthreads();
  if (threadIdx.x == 0) {
    float tot = red[0] + red[1] + red[2] + red[3];
    inv_den[row] = 1.f / (tot * (1.f / DM) + 1e-5f);
  }
}

// ---------------------------------------------------------------------------
// Pass A: per-(head,chunk) sums of k (x) v outer products and k.
// Thread (g = tid>>6, m = tid&63) owns kv[d = g*16+j][m].
// ---------------------------------------------------------------------------
__global__ __launch_bounds__(256) void chunk_sum_kernel(const float* __restrict__ Ko,
                                                        const float* __restrict__ Vo,
                                                        float* __restrict__ Skv,
                                                        float* __restrict__ Sk) {
  const int h = blockIdx.x >> 4;
  const int c = blockIdx.x & 15;
  const int tid = threadIdx.x;
  const int m = tid & 63, g = tid >> 6;
  __shared__ float kL[64], vL[64];
  float kv[16];
#pragma unroll
  for (int j = 0; j < 16; j++) kv[j] = 0.f;
  float ks = 0.f;
  const float* Kb = Ko + ((size_t)h * T_SEQ + c * CHUNK) * DH;
  const float* Vb = Vo + ((size_t)h * T_SEQ + c * CHUNK) * DH;
  for (int t = 0; t < CHUNK; t++) {
    __syncthreads();
    if (tid < 64) kL[tid] = Kb[t * 64 + tid];
    else if (tid < 128) vL[tid - 64] = Vb[t * 64 + tid - 64];
    __syncthreads();
    const float vm = vL[m];
#pragma unroll
    for (int j = 0; j < 16; j++) kv[j] += kL[g * 16 + j] * vm;
    if (tid < 64) ks += kL[tid];
  }
  float* outp = Skv + (size_t)blockIdx.x * 4096;
#pragma unroll
  for (int j = 0; j < 16; j++) outp[(g * 16 + j) * 64 + m] = kv[j];
  if (tid < 64) Sk[blockIdx.x * 64 + tid] = ks;
}

// ---------------------------------------------------------------------------
// Pass B: in-place exclusive prefix over chunks (per head). Grid = NH.
// ---------------------------------------------------------------------------
__global__ __launch_bounds__(256) void chunk_scan_kernel(float* __restrict__ Skv,
                                                         float* __restrict__ Sk) {
  const int h = blockIdx.x;
  for (int e = threadIdx.x; e < 4096; e += 256) {
    float acc = 0.f;
    for (int c = 0; c < NCHUNK; c++) {
      float* p = Skv + ((size_t)(h * NCHUNK + c)) * 4096 + e;
      float s = *p;
      *p = acc;
      acc += s;
    }
  }
  if (threadIdx.x < 64) {
    const int e = threadIdx.x;
    float acc = 0.f;
    for (int c = 0; c < NCHUNK; c++) {
      float* p = Sk + (h * NCHUNK + c) * 64 + e;
      float s = *p;
      *p = acc;
      acc += s;
    }
  }
}

// ---------------------------------------------------------------------------
// Pass C: within-chunk inclusive scan + output emit (bf16 [T][DM] for proj).
// ---------------------------------------------------------------------------
__global__ __launch_bounds__(256) void attn_out_kernel(const float* __restrict__ Qo,
                                                       const float* __restrict__ Ko,
                                                       const float* __restrict__ Vo,
                                                       const float* __restrict__ Skv,
                                                       const float* __restrict__ Sk,
                                                       bf16* __restrict__ O) {
  const int h = blockIdx.x >> 4;
  const int c = blockIdx.x & 15;
  const int tid = threadIdx.x;
  const int m = tid & 63, g = tid >> 6;
  __shared__ float qL[64], kL[64], vL[64], kcumL[64], numpart[256];
  float kv[16];
  const float* Sb = Skv + (size_t)blockIdx.x * 4096;
#pragma unroll
  for (int j = 0; j < 16; j++) kv[j] = Sb[(g * 16 + j) * 64 + m];
  if (tid < 64) kcumL[tid] = Sk[blockIdx.x * 64 + tid];
  const size_t base = ((size_t)h * T_SEQ + c * CHUNK) * DH;
  for (int t = 0; t < CHUNK; t++) {
    __syncthreads();
    if (tid < 64) qL[tid] = Qo[base + t * 64 + tid];
    else if (tid < 128) kL[tid - 64] = Ko[base + t * 64 + tid - 64];
    else if (tid < 192) vL[tid - 128] = Vo[base + t * 64 + tid - 128];
    __syncthreads();
    const float vm = vL[m];
    float np = 0.f;
#pragma unroll
    for (int j = 0; j < 16; j++) {
      kv[j] += kL[g * 16 + j] * vm;   // inclusive state update
      np += qL[g * 16 + j] * kv[j];
    }
    numpart[g * 64 + m] = np;
    if (tid < 64) kcumL[tid] += kL[tid];
    __syncthreads();
    if (tid < 64) {
      float p = qL[tid] * kcumL[tid];
#pragma unroll
      for (int msk = 1; msk < 64; msk <<= 1) p += __shfl_xor(p, msk, 64);
      const float num = numpart[tid] + numpart[64 + tid] + numpart[128 + tid] + numpart[192 + tid];
      const int tg = c * CHUNK + t;
      O[(size_t)tg * DM + h * 64 + tid] = __float2bfloat16(num / (p + 1e-5f));
    }
  }
}

// ---------------------------------------------------------------------------
extern "C" void kernel_launch(void* const* d_in, const int* in_sizes, int n_in,
                              void* d_out, int out_size, void* d_ws, size_t ws_size,
                              hipStream_t stream) {
  (void)in_sizes; (void)n_in; (void)out_size; (void)ws_size;
  const float* x      = (const float*)d_in[0];
  const float* ln_g   = (const float*)d_in[1];
  const float* ln_b   = (const float*)d_in[2];
  const float* qkv_w  = (const float*)d_in[3];
  const float* qkv_b  = (const float*)d_in[4];
  const float* gate_w = (const float*)d_in[5];
  const float* gate_b = (const float*)d_in[6];
  const float* proj_w = (const float*)d_in[7];
  const float* proj_b = (const float*)d_in[8];
  float* out = (float*)d_out;

  char* ws = (char*)d_ws;
  size_t off = 0;
  auto alloc = [&](size_t bytes) {
    void* p = ws + off;
    off += (bytes + 255) & ~(size_t)255;
    return p;
  };
  bf16*  xn       = (bf16*)alloc((size_t)T_SEQ * DM * 2);
  bf16*  xbf      = (bf16*)alloc((size_t)T_SEQ * DM * 2);
  bf16*  wqkv     = (bf16*)alloc((size_t)3 * DM * DM * 2);
  bf16*  wgate    = (bf16*)alloc((size_t)DM * DM * 2);
  bf16*  wproj    = (bf16*)alloc((size_t)DM * DM * 2);
  float* gate_sig = (float*)alloc((size_t)T_SEQ * DM * 4);
  float* inv_den  = (float*)alloc((size_t)T_SEQ * 4);
  float* Qo       = (float*)alloc((size_t)T_SEQ * DM * 4);
  float* Ko       = (float*)alloc((size_t)T_SEQ * DM * 4);
  float* Vo       = (float*)alloc((size_t)T_SEQ * DM * 4);
  bf16*  Obuf     = (bf16*)alloc((size_t)T_SEQ * DM * 2);
  float* Skv      = (float*)alloc((size_t)NH * NCHUNK * 4096 * 4);
  float* Sk       = (float*)alloc((size_t)NH * NCHUNK * 64 * 4);

  const int n4_qkv  = 3 * DM * DM / 4;
  const int n4_sq   = DM * DM / 4;
  f2b_kernel<<<(n4_qkv + 255) / 256, 256, 0, stream>>>(qkv_w, wqkv, n4_qkv);
  f2b_kernel<<<(n4_sq + 255) / 256, 256, 0, stream>>>(gate_w, wgate, n4_sq);
  f2b_kernel<<<(n4_sq + 255) / 256, 256, 0, stream>>>(proj_w, wproj, n4_sq);

  ln_kernel<<<T_SEQ, 256, 0, stream>>>(x, ln_g, ln_b, xn, xbf);
  gemm_bt<0><<<dim3(16, 8), 256, 0, stream>>>(xbf, wgate, gate_b, gate_sig, nullptr,
                                              nullptr, nullptr, nullptr, nullptr);
  gate_mean_kernel<<<T_SEQ, 256, 0, stream>>>(gate_sig, inv_den);
  gemm_bt<1><<<dim3(16, 24), 256, 0, stream>>>(xn, wqkv, qkv_b, gate_sig, inv_den,
                                               Qo, Ko, Vo, nullptr);
  chunk_sum_kernel<<<NH * NCHUNK, 256, 0, stream>>>(Ko, Vo, Skv, Sk);
  chunk_scan_kernel<<<NH, 256, 0, stream>>>(Skv, Sk);
  attn_out_kernel<<<NH * NCHUNK, 256, 0, stream>>>(Qo, Ko, Vo, Skv, Sk, Obuf);
  gemm_bt<2><<<dim3(16, 8), 256, 0, stream>>>(Obuf, wproj, proj_b, nullptr, nullptr,
                                              nullptr, nullptr, nullptr, out);
}